// Round 3
// baseline (2210.718 us; speedup 1.0000x reference)
//
#include <hip/hip_runtime.h>

#define NEG_SLOPE 0.01f
#define CSHIFT 13               // 8192 rows per coarse bucket (<=49 coarse for N<=400k)
#define MSHIFT 7                // 128 rows per mid bucket
#define MPC (1 << (CSHIFT - MSHIFT))   // 64 mids per coarse
#define MWIN 192                // window of mid-counters per split tile (straddle<=2 coarse)
#define CAP 4096                // max edges per mid bucket in csr_sort LDS
#define TILE_E 2048             // edges per split tile

typedef _Float16 half_t;
typedef _Float16 half2_t __attribute__((ext_vector_type(2)));
typedef _Float16 half4_t __attribute__((ext_vector_type(4)));

static inline int cdiv(long long a, long long b) { return (int)((a + b - 1) / b); }

__global__ __launch_bounds__(256) void zero_i32(int* __restrict__ p, int n) {
    int i = blockIdx.x * 256 + threadIdx.x;
    if (i < n) p[i] = 0;
}

// ---- coarse histogram: LDS counters, one merge atomic per (block,bucket) ----
__global__ __launch_bounds__(256) void hist_coarse(const int* __restrict__ rows, int* __restrict__ ccnt, int E) {
    __shared__ int cnt[64];
    int t = threadIdx.x;
    if (t < 64) cnt[t] = 0;
    __syncthreads();
    int base = blockIdx.x * TILE_E;
#pragma unroll
    for (int k = 0; k < TILE_E / 256; k++) {
        int e = base + k * 256 + t;
        if (e < E) atomicAdd(&cnt[rows[e] >> CSHIFT], 1);
    }
    __syncthreads();
    if (t < 64 && cnt[t] > 0) atomicAdd(&ccnt[t], cnt[t]);
}

__global__ void scan_coarse(const int* __restrict__ ccnt, int* __restrict__ cbase,
                            int* __restrict__ cfront, int NBc, int E) {
    if (threadIdx.x == 0 && blockIdx.x == 0) {
        int run = 0;
        for (int b = 0; b < NBc; b++) { cbase[b] = run; cfront[b] = run; run += ccnt[b]; }
        cbase[NBc] = E;
    }
}

// ---- pass A: LDS multisplit into coarse buckets; dense chunk writes ----
// record: ( (row & 8191) << 19 | col , val )   [13+19 = 32 bits exactly, col < 2^19]
__global__ __launch_bounds__(256) void split_coarse(
    const int* __restrict__ rows, const int* __restrict__ cols, const float* __restrict__ vals,
    int* __restrict__ cfront, int2* __restrict__ stg1, int E)
{
    __shared__ int cnt[64], gb[64];
    int t = threadIdx.x;
    if (t < 64) cnt[t] = 0;
    __syncthreads();
    int base = blockIdx.x * TILE_E;
    int myb[8], myrank[8]; int2 mycv[8];
#pragma unroll
    for (int k = 0; k < 8; k++) {
        int e = base + k * 256 + t;
        myb[k] = -1;
        if (e < E) {
            int r = rows[e];
            int b = r >> CSHIFT;
            mycv[k] = make_int2((int)(((unsigned)(r & ((1 << CSHIFT) - 1)) << 19) | (unsigned)cols[e]),
                                __float_as_int(vals[e]));
            myb[k] = b;
            myrank[k] = atomicAdd(&cnt[b], 1);
        }
    }
    __syncthreads();
    if (t < 64 && cnt[t] > 0) gb[t] = atomicAdd(&cfront[t], cnt[t]);
    __syncthreads();
#pragma unroll
    for (int k = 0; k < 8; k++)
        if (myb[k] >= 0) stg1[gb[myb[k]] + myrank[k]] = mycv[k];
}

// ---- mid histogram from coarse-sorted staging (windowed LDS counters) ----
__global__ __launch_bounds__(256) void hist_mid(
    const int2* __restrict__ stg1, const int* __restrict__ cbase_g,
    int* __restrict__ mcnt, int E, int NBc)
{
    __shared__ int cb[66];
    __shared__ int wc[MWIN];
    int t = threadIdx.x;
    for (int i = t; i <= NBc; i += 256) cb[i] = cbase_g[i];
    for (int i = t; i < MWIN; i += 256) wc[i] = 0;
    __syncthreads();
    int base = blockIdx.x * TILE_E;
    int lo = 0, hi = NBc - 1;
    while (lo < hi) { int m = (lo + hi + 1) >> 1; if (cb[m] <= base) lo = m; else hi = m - 1; }
    int winm = lo * MPC;
#pragma unroll
    for (int k = 0; k < 8; k++) {
        int e = base + k * 256 + t;
        if (e < E) {
            int b = lo;
            while (cb[b + 1] <= e) b++;
            int m = b * MPC + (int)(((unsigned)stg1[e].x >> 19) >> MSHIFT);
            int lf = m - winm;
            if (lf >= 0 && lf < MWIN) atomicAdd(&wc[lf], 1);
            else atomicAdd(&mcnt[m], 1);    // rare fallback
        }
    }
    __syncthreads();
    for (int i = t; i < MWIN; i += 256)
        if (wc[i] > 0) atomicAdd(&mcnt[winm + i], wc[i]);
}

// ---- single-block scan over mid buckets (NBm <= 3125) -> mbase, mfront ----
__global__ __launch_bounds__(256) void scan_mid(
    const int* __restrict__ mcnt, int* __restrict__ mbase,
    int* __restrict__ mfront, int NBm, int E)
{
    __shared__ int sd[256];
    __shared__ int carry;
    int t = threadIdx.x;
    if (t == 0) carry = 0;
    __syncthreads();
    for (int base = 0; base < NBm; base += 256) {
        int v = (base + t < NBm) ? mcnt[base + t] : 0;
        sd[t] = v;
        __syncthreads();
        for (int off = 1; off < 256; off <<= 1) {
            int x = (t >= off) ? sd[t - off] : 0;
            __syncthreads();
            sd[t] += x;
            __syncthreads();
        }
        int incl = sd[t] + carry;
        int excl = incl - v;
        if (base + t < NBm) { mbase[base + t] = excl; mfront[base + t] = excl; }
        __syncthreads();
        if (t == 255) carry = incl;
        __syncthreads();
    }
    if (t == 0) mbase[NBm] = E;
}

// ---- pass B: coarse-sorted staging -> mid (128-row) buckets; windowed LDS ranking ----
__global__ __launch_bounds__(256) void split_mid(
    const int2* __restrict__ stg1, const int* __restrict__ cbase_g,
    int* __restrict__ mfront, int2* __restrict__ stgm, int E, int NBc)
{
    __shared__ int cb[66];
    __shared__ int wc[MWIN], wg[MWIN];
    int t = threadIdx.x;
    for (int i = t; i <= NBc; i += 256) cb[i] = cbase_g[i];
    for (int i = t; i < MWIN; i += 256) wc[i] = 0;
    __syncthreads();
    int base = blockIdx.x * TILE_E;
    int lo = 0, hi = NBc - 1;
    while (lo < hi) { int m = (lo + hi + 1) >> 1; if (cb[m] <= base) lo = m; else hi = m - 1; }
    int winm = lo * MPC;
    int mylf[8], myrank[8]; int2 myp[8];
#pragma unroll
    for (int k = 0; k < 8; k++) {
        int e = base + k * 256 + t;
        mylf[k] = -1;
        if (e < E) {
            int b = lo;
            while (cb[b + 1] <= e) b++;
            int2 cv = stg1[e];
            int m = (b << (CSHIFT - MSHIFT)) + (int)(((unsigned)cv.x >> 19) >> MSHIFT);
            int lf = m - winm;
            if (lf >= 0 && lf < MWIN) { mylf[k] = lf; myrank[k] = atomicAdd(&wc[lf], 1); myp[k] = cv; }
            else stgm[atomicAdd(&mfront[m], 1)] = cv;   // rare fallback
        }
    }
    __syncthreads();
    for (int i = t; i < MWIN; i += 256)
        if (wc[i] > 0) wg[i] = atomicAdd(&mfront[winm + i], wc[i]);
    __syncthreads();
#pragma unroll
    for (int k = 0; k < 8; k++)
        if (mylf[k] >= 0) stgm[wg[mylf[k]] + myrank[k]] = myp[k];
}

// ---- pass C: one block per mid bucket; LDS counting sort to exact CSR ----
__global__ __launch_bounds__(256) void csr_sort(
    const int2* __restrict__ stgm, const int* __restrict__ mbase,
    int* __restrict__ rowptr, int2* __restrict__ ecv, int N)
{
    __shared__ int2 buf[CAP];
    __shared__ int cnt[128], sc[128], front[128];
    int mb = blockIdx.x, t = threadIdx.x;
    int row0 = mb << MSHIFT;
    int nrows = N - row0; if (nrows > 128) nrows = 128;
    int s = mbase[mb], eend = mbase[mb + 1];
    if (t < 128) cnt[t] = 0;
    __syncthreads();
    for (int i = s + t; i < eend; i += 256)
        atomicAdd(&cnt[((unsigned)stgm[i].x >> 19) & 127], 1);
    __syncthreads();
    if (t < 128) sc[t] = cnt[t];
    __syncthreads();
    for (int off = 1; off < 128; off <<= 1) {
        int x = (t >= off && t < 128) ? sc[t - off] : 0;
        __syncthreads();
        if (t < 128) sc[t] += x;
        __syncthreads();
    }
    if (t < 128) front[t] = sc[t] - cnt[t];
    if (t < nrows) rowptr[row0 + t] = s + sc[t] - cnt[t];
    if (t == 0 && row0 + nrows == N) rowptr[N] = eend;
    __syncthreads();
    for (int i = s + t; i < eend; i += 256) {
        int2 cv = stgm[i];
        unsigned p = (unsigned)cv.x;
        int rl = ((int)(p >> 19)) & 127;
        int2 rec = make_int2((int)(p & 0x7FFFFu), cv.y);
        int l = atomicAdd(&front[rl], 1);
        if (l < CAP) buf[l] = rec;
        else ecv[s + l] = rec;               // overflow fallback (statistically never)
    }
    __syncthreads();
    int total = eend - s; if (total > CAP) total = CAP;
    for (int l = t; l < total; l += 256) ecv[s + l] = buf[l];
}

// Layer-1 dense only: H[n,:] = x@Wtop + b ; Z[n,:] = x@Wbot (fp16, stride 32 halfs)
template<int COUT, bool LRELU>
__global__ __launch_bounds__(256) void dense_kernel(
    const float* in, const float* __restrict__ W,
    const float* __restrict__ b, float* H,
    half_t* __restrict__ Z, int N)
{
    int n = blockIdx.x * 256 + threadIdx.x;
    if (n >= N) return;
    const float* row = in + (size_t)n * 32;
    float xv[32];
#pragma unroll
    for (int f = 0; f < 32; f += 4) {
        float4 v = *(const float4*)(row + f);
        xv[f] = v.x; xv[f + 1] = v.y; xv[f + 2] = v.z; xv[f + 3] = v.w;
    }
    if (LRELU) {
#pragma unroll
        for (int f = 0; f < 32; f++) xv[f] = xv[f] > 0.f ? xv[f] : NEG_SLOPE * xv[f];
    }
    float acct[COUT], accb[COUT];
#pragma unroll
    for (int c = 0; c < COUT; c++) { acct[c] = b[c]; accb[c] = 0.f; }
#pragma unroll 4
    for (int f = 0; f < 32; f++) {
        float xf = xv[f];
#pragma unroll
        for (int c = 0; c < COUT; c++) {
            acct[c] = fmaf(xf, W[f * COUT + c], acct[c]);
            accb[c] = fmaf(xf, W[(32 + f) * COUT + c], accb[c]);
        }
    }
    float* hrow = H + (size_t)n * 32;
    half_t* zrow = Z + (size_t)n * 32;
#pragma unroll
    for (int c = 0; c < COUT; c++) hrow[c] = acct[c];
#pragma unroll
    for (int c = 0; c < COUT; c += 2) {
        half2_t h;
        h.x = (half_t)accb[c];
        h.y = (half_t)accb[c + 1];
        *(half2_t*)(zrow + c) = h;
    }
}

// CSR gather (32-wide, 8 lanes x half4, 2 row-chains/thread) FUSED with the NEXT
// layer's dense: epilogue computes Htop_{l+1} = lrelu(Hfin)@Wn[0:32] + bn and
// Z_{l+1} = lrelu(Hfin)@Wn[32:64] from registers via intra-group shuffles.
// NOTE: Hbase/Hn/Zn may alias (own-row in-place) -> NO __restrict__ on them.
template<int ZC>   // next-layer output count: 32 or 10
__global__ __launch_bounds__(256) void gather_fused(
    const int* __restrict__ rowptr, const int2* __restrict__ ecv,
    const half_t* __restrict__ Z, const float* Hbase,
    const float* __restrict__ Wn, const float* __restrict__ bn,
    float* Hn, half_t* Zn, int hnStride, int znStride, int N)
{
    __shared__ float Ws[64 * ZC];
    __shared__ float bs[ZC];
    int t = threadIdx.x;
    for (int i = t; i < 64 * ZC; i += 256) Ws[i] = Wn[i];
    if (t < ZC) bs[t] = bn[t];
    __syncthreads();                 // no barriers after this point
    int tid = blockIdx.x * 256 + t;
    int pr = tid >> 3, lane = tid & 7;
    int r0 = pr * 2, r1 = r0 + 1;
    if (r0 >= N) return;             // group-uniform (pr shared by all 8 lanes)
    bool v1 = (r1 < N);
    int s0 = rowptr[r0], e0 = rowptr[r0 + 1];
    int s1 = 0, e1 = 0;
    if (v1) { s1 = rowptr[r1]; e1 = rowptr[r1 + 1]; }
    float ax0 = 0.f, ay0 = 0.f, az0 = 0.f, aw0 = 0.f;
    float ax1 = 0.f, ay1 = 0.f, az1 = 0.f, aw1 = 0.f;
    int i0 = s0, i1 = s1;
    while (i0 < e0 && i1 < e1) {
        int2 c0 = ecv[i0]; int2 c1 = ecv[i1];
        half4_t z0 = *(const half4_t*)(Z + (size_t)c0.x * 32 + lane * 4);
        half4_t z1 = *(const half4_t*)(Z + (size_t)c1.x * 32 + lane * 4);
        float v0 = __int_as_float(c0.y), vv1 = __int_as_float(c1.y);
        ax0 = fmaf(v0, (float)z0.x, ax0); ay0 = fmaf(v0, (float)z0.y, ay0);
        az0 = fmaf(v0, (float)z0.z, az0); aw0 = fmaf(v0, (float)z0.w, aw0);
        ax1 = fmaf(vv1, (float)z1.x, ax1); ay1 = fmaf(vv1, (float)z1.y, ay1);
        az1 = fmaf(vv1, (float)z1.z, az1); aw1 = fmaf(vv1, (float)z1.w, aw1);
        i0++; i1++;
    }
    for (; i0 < e0; i0++) {
        int2 c0 = ecv[i0];
        half4_t z0 = *(const half4_t*)(Z + (size_t)c0.x * 32 + lane * 4);
        float v0 = __int_as_float(c0.y);
        ax0 = fmaf(v0, (float)z0.x, ax0); ay0 = fmaf(v0, (float)z0.y, ay0);
        az0 = fmaf(v0, (float)z0.z, az0); aw0 = fmaf(v0, (float)z0.w, aw0);
    }
    for (; i1 < e1; i1++) {
        int2 c1 = ecv[i1];
        half4_t z1 = *(const half4_t*)(Z + (size_t)c1.x * 32 + lane * 4);
        float vv1 = __int_as_float(c1.y);
        ax1 = fmaf(vv1, (float)z1.x, ax1); ay1 = fmaf(vv1, (float)z1.y, ay1);
        az1 = fmaf(vv1, (float)z1.z, az1); aw1 = fmaf(vv1, (float)z1.w, aw1);
    }
    // Hfin = Htop_base + gather sum (each row owned by exactly this thread)
    float4 h0 = *(const float4*)(Hbase + (size_t)r0 * 32 + lane * 4);
    h0.x += ax0; h0.y += ay0; h0.z += az0; h0.w += aw0;
    float4 h1 = make_float4(0.f, 0.f, 0.f, 0.f);
    if (v1) {
        h1 = *(const float4*)(Hbase + (size_t)r1 * 32 + lane * 4);
        h1.x += ax1; h1.y += ay1; h1.z += az1; h1.w += aw1;
    }
    // leaky-relu (activation between layers)
    float4 a0, a1;
    a0.x = h0.x > 0.f ? h0.x : NEG_SLOPE * h0.x;
    a0.y = h0.y > 0.f ? h0.y : NEG_SLOPE * h0.y;
    a0.z = h0.z > 0.f ? h0.z : NEG_SLOPE * h0.z;
    a0.w = h0.w > 0.f ? h0.w : NEG_SLOPE * h0.w;
    a1.x = h1.x > 0.f ? h1.x : NEG_SLOPE * h1.x;
    a1.y = h1.y > 0.f ? h1.y : NEG_SLOPE * h1.y;
    a1.z = h1.z > 0.f ? h1.z : NEG_SLOPE * h1.z;
    a1.w = h1.w > 0.f ? h1.w : NEG_SLOPE * h1.w;
    // ---- fused next-layer dense: group-shuffle broadcast of the 32-wide row ----
    constexpr int CPL = (ZC == 32) ? 4 : 2;
    int cl = (ZC == 32) ? lane : (lane < 5 ? lane : 4);   // lanes 5-7 compute dummy (shfl sources must run)
    int c0c = cl * CPL;
    float T0[CPL], T1[CPL], Q0[CPL], Q1[CPL];
#pragma unroll
    for (int cc = 0; cc < CPL; cc++) { T0[cc] = bs[c0c + cc]; T1[cc] = bs[c0c + cc]; Q0[cc] = 0.f; Q1[cc] = 0.f; }
#pragma unroll
    for (int k = 0; k < 8; k++) {
        float f0a[4], f1a[4];
        f0a[0] = __shfl(a0.x, k, 8); f0a[1] = __shfl(a0.y, k, 8);
        f0a[2] = __shfl(a0.z, k, 8); f0a[3] = __shfl(a0.w, k, 8);
        f1a[0] = __shfl(a1.x, k, 8); f1a[1] = __shfl(a1.y, k, 8);
        f1a[2] = __shfl(a1.z, k, 8); f1a[3] = __shfl(a1.w, k, 8);
#pragma unroll
        for (int q = 0; q < 4; q++) {
            int f = 4 * k + q;
#pragma unroll
            for (int cc = 0; cc < CPL; cc++) {
                float wt = Ws[f * ZC + c0c + cc];
                float wb = Ws[(32 + f) * ZC + c0c + cc];
                T0[cc] = fmaf(f0a[q], wt, T0[cc]);
                Q0[cc] = fmaf(f0a[q], wb, Q0[cc]);
                T1[cc] = fmaf(f1a[q], wt, T1[cc]);
                Q1[cc] = fmaf(f1a[q], wb, Q1[cc]);
            }
        }
    }
    if (ZC == 32 || lane < 5) {
        float* hp0 = Hn + (size_t)r0 * hnStride + c0c;
        half_t* zp0 = Zn + (size_t)r0 * znStride + c0c;
        if (ZC == 32) {
            *(float4*)hp0 = make_float4(T0[0], T0[1], T0[2], T0[3]);
            half4_t z4; z4.x = (half_t)Q0[0]; z4.y = (half_t)Q0[1]; z4.z = (half_t)Q0[2]; z4.w = (half_t)Q0[3];
            *(half4_t*)zp0 = z4;
        } else {
            *(float2*)hp0 = make_float2(T0[0], T0[1]);
            half2_t z2; z2.x = (half_t)Q0[0]; z2.y = (half_t)Q0[1];
            *(half2_t*)zp0 = z2;
        }
        if (v1) {
            float* hp1 = Hn + (size_t)r1 * hnStride + c0c;
            half_t* zp1 = Zn + (size_t)r1 * znStride + c0c;
            if (ZC == 32) {
                *(float4*)hp1 = make_float4(T1[0], T1[1], T1[2], T1[3]);
                half4_t z4; z4.x = (half_t)Q1[0]; z4.y = (half_t)Q1[1]; z4.z = (half_t)Q1[2]; z4.w = (half_t)Q1[3];
                *(half4_t*)zp1 = z4;
            } else {
                *(float2*)hp1 = make_float2(T1[0], T1[1]);
                half2_t z2; z2.x = (half_t)Q1[0]; z2.y = (half_t)Q1[1];
                *(half2_t*)zp1 = z2;
            }
        }
    }
}

// Final 10-wide gather: Z3 stride 64 halfs (own-row slots in bufA), H packed stride 16
__global__ __launch_bounds__(256) void gather10(
    const int* __restrict__ rowptr, const int2* __restrict__ ecv,
    const half_t* __restrict__ Z, float* H, int N)
{
    int tid = blockIdx.x * 256 + threadIdx.x;
    int pr = tid >> 3, lane = tid & 7;
    int r0 = pr * 2, r1 = r0 + 1;
    if (r0 >= N || lane >= 5) return;
    int s0 = rowptr[r0], e0 = rowptr[r0 + 1];
    int s1 = 0, e1 = 0;
    if (r1 < N) { s1 = rowptr[r1]; e1 = rowptr[r1 + 1]; }
    float ax0 = 0.f, ay0 = 0.f, ax1 = 0.f, ay1 = 0.f;
    int i0 = s0, i1 = s1;
    while (i0 < e0 && i1 < e1) {
        int2 c0 = ecv[i0]; int2 c1 = ecv[i1];
        half2_t z0 = *(const half2_t*)(Z + (size_t)c0.x * 64 + lane * 2);
        half2_t z1 = *(const half2_t*)(Z + (size_t)c1.x * 64 + lane * 2);
        float v0 = __int_as_float(c0.y), v1 = __int_as_float(c1.y);
        ax0 = fmaf(v0, (float)z0.x, ax0); ay0 = fmaf(v0, (float)z0.y, ay0);
        ax1 = fmaf(v1, (float)z1.x, ax1); ay1 = fmaf(v1, (float)z1.y, ay1);
        i0++; i1++;
    }
    for (; i0 < e0; i0++) {
        int2 c0 = ecv[i0];
        half2_t z0 = *(const half2_t*)(Z + (size_t)c0.x * 64 + lane * 2);
        float v0 = __int_as_float(c0.y);
        ax0 = fmaf(v0, (float)z0.x, ax0); ay0 = fmaf(v0, (float)z0.y, ay0);
    }
    for (; i1 < e1; i1++) {
        int2 c1 = ecv[i1];
        half2_t z1 = *(const half2_t*)(Z + (size_t)c1.x * 64 + lane * 2);
        float v1 = __int_as_float(c1.y);
        ax1 = fmaf(v1, (float)z1.x, ax1); ay1 = fmaf(v1, (float)z1.y, ay1);
    }
    float* hp0 = H + (size_t)r0 * 16 + lane * 2;
    hp0[0] += ax0; hp0[1] += ay0;
    if (r1 < N) {
        float* hp1 = H + (size_t)r1 * 16 + lane * 2;
        hp1[0] += ax1; hp1[1] += ay1;
    }
}

// one block per graph; H packed stride 16
__global__ __launch_bounds__(256) void pool_graph(
    const float* __restrict__ H, const int* __restrict__ batch,
    float* __restrict__ pool, int N, int dimoff)
{
    int g = blockIdx.x;
    int lo = 0, hi = N;
    while (lo < hi) { int mid = (lo + hi) >> 1; if (batch[mid] < g) lo = mid + 1; else hi = mid; }
    int start = lo;
    lo = start; hi = N;
    while (lo < hi) { int mid = (lo + hi) >> 1; if (batch[mid] < g + 1) lo = mid + 1; else hi = mid; }
    int end = lo;
    int t = threadIdx.x, f = t & 15, chain = t >> 4;
    __shared__ float sd[256];
    float acc = 0.f;
    if (f < 10) {
        for (int i = start + chain; i < end; i += 16) acc += H[(size_t)i * 16 + f];
    }
    sd[t] = acc; __syncthreads();
    if (chain == 0 && f < 10) {
        float s = 0.f;
#pragma unroll
        for (int k = 0; k < 16; k++) s += sd[k * 16 + f];
        int c = end - start;
        float inv = 1.f / (float)(c > 1 ? c : 1);
        pool[(size_t)g * 30 + dimoff + f] = s * inv;
    }
}

__global__ __launch_bounds__(256) void final_kernel(
    const float* __restrict__ pool, const float* __restrict__ Wf,
    const float* __restrict__ bfv, float* __restrict__ out, int G)
{
    int g = blockIdx.x * 256 + threadIdx.x;
    if (g >= G) return;
    float m[30];
#pragma unroll
    for (int j = 0; j < 30; j++) m[j] = pool[(size_t)g * 30 + j];
    float lg[10];
#pragma unroll
    for (int o = 0; o < 10; o++) {
        float a = bfv[o];
#pragma unroll
        for (int j = 0; j < 30; j++) a = fmaf(m[j], Wf[j * 10 + o], a);
        lg[o] = a;
    }
    float mx = lg[0];
#pragma unroll
    for (int o = 1; o < 10; o++) mx = fmaxf(mx, lg[o]);
    float s = 0.f;
#pragma unroll
    for (int o = 0; o < 10; o++) { lg[o] = __expf(lg[o] - mx); s += lg[o]; }
    float invs = 1.f / s;
#pragma unroll
    for (int o = 0; o < 10; o++) out[(size_t)g * 10 + o] = lg[o] * invs;
}

extern "C" void kernel_launch(void* const* d_in, const int* in_sizes, int n_in,
                              void* d_out, int out_size, void* d_ws, size_t ws_size,
                              hipStream_t stream)
{
    (void)n_in; (void)ws_size;
    const float* x[3]    = {(const float*)d_in[0], (const float*)d_in[1], (const float*)d_in[2]};
    const float* vals[3] = {(const float*)d_in[3], (const float*)d_in[4], (const float*)d_in[5]};
    const int* rows[3]   = {(const int*)d_in[6], (const int*)d_in[8], (const int*)d_in[10]};
    const int* cols[3]   = {(const int*)d_in[7], (const int*)d_in[9], (const int*)d_in[11]};
    const int* batch[3]  = {(const int*)d_in[12], (const int*)d_in[13], (const int*)d_in[14]};
    const float* W1[3] = {(const float*)d_in[16], (const float*)d_in[22], (const float*)d_in[28]};
    const float* b1[3] = {(const float*)d_in[17], (const float*)d_in[23], (const float*)d_in[29]};
    const float* W2[3] = {(const float*)d_in[18], (const float*)d_in[24], (const float*)d_in[30]};
    const float* b2[3] = {(const float*)d_in[19], (const float*)d_in[25], (const float*)d_in[31]};
    const float* W3[3] = {(const float*)d_in[20], (const float*)d_in[26], (const float*)d_in[32]};
    const float* b3[3] = {(const float*)d_in[21], (const float*)d_in[27], (const float*)d_in[33]};
    const float* Wf  = (const float*)d_in[34];
    const float* bfv = (const float*)d_in[35];
    float* out = (float*)d_out;

    int N[3] = {in_sizes[0] / 32, in_sizes[1] / 32, in_sizes[2] / 32};
    int E[3] = {in_sizes[3], in_sizes[4], in_sizes[5]};
    int G = out_size / 10;
    int maxN = N[0]; if (N[1] > maxN) maxN = N[1]; if (N[2] > maxN) maxN = N[2];
    int maxE = E[0]; if (E[1] > maxE) maxE = E[1]; if (E[2] > maxE) maxE = E[2];
    int maxNBm = cdiv(maxN, 1 << MSHIFT);

    // Workspace (same total as before: bufA 32f + two 16f Z halves = 64f per node):
    float* bufA = (float*)d_ws;                      // Htop1/2 (stride 32); Z3 own-row half slots; stgm alias
    float* ZhAf = bufA + (size_t)maxN * 32;          // Z1 (halfs, stride 32) / Htop3+Hfin3 packed stride 16; stg1 alias
    float* ZhBf = ZhAf + (size_t)maxN * 16;          // Z2 (halfs, stride 32)
    float* pool = ZhBf + (size_t)maxN * 16;
    int2*  ecv    = (int2*)(pool + (size_t)G * 30 + 2); // +2 for int2 alignment
    int*   rowptr = (int*)(ecv + maxE);
    int*   mcnt   = rowptr + (maxN + 1);
    int*   mbase  = mcnt + maxNBm;
    int*   mfront = mbase + (maxNBm + 1);
    int*   ccnt   = mfront + maxNBm;
    int*   cbase  = ccnt + 64;
    int*   cfront = cbase + 66;
    int2*  stg1 = (int2*)ZhAf;                       // build-phase only (maxE*8B == maxN*16*4B)
    int2*  stgm = (int2*)bufA;                       // build-phase only
    half_t* ZhA = (half_t*)ZhAf;
    half_t* ZhB = (half_t*)ZhBf;

    for (int d = 0; d < 3; d++) {
        int n = N[d], e = E[d];
        int NBc = cdiv(n, 1 << CSHIFT);
        int NBm = cdiv(n, 1 << MSHIFT);
        int ntile = cdiv(e, TILE_E);
        int gsz = cdiv((long long)cdiv(n, 2) * 8, 256);

        // --- coarse split -> mid split -> in-block CSR sort ---
        zero_i32<<<1, 256, 0, stream>>>(ccnt, 64);
        hist_coarse<<<ntile, 256, 0, stream>>>(rows[d], ccnt, e);
        scan_coarse<<<1, 64, 0, stream>>>(ccnt, cbase, cfront, NBc, e);
        split_coarse<<<ntile, 256, 0, stream>>>(rows[d], cols[d], vals[d], cfront, stg1, e);
        zero_i32<<<cdiv(NBm, 256), 256, 0, stream>>>(mcnt, NBm);
        hist_mid<<<ntile, 256, 0, stream>>>(stg1, cbase, mcnt, e, NBc);
        scan_mid<<<1, 256, 0, stream>>>(mcnt, mbase, mfront, NBm, e);
        split_mid<<<ntile, 256, 0, stream>>>(stg1, cbase, mfront, stgm, e, NBc);
        csr_sort<<<NBm, 256, 0, stream>>>(stgm, mbase, rowptr, ecv, n);

        // --- layer 1 dense, then gathers with fused next-layer dense epilogues ---
        dense_kernel<32, false><<<cdiv(n, 256), 256, 0, stream>>>(x[d], W1[d], b1[d], bufA, ZhA, n);
        // gather L1 (+ dense L2): reads Z1(ZhA), Htop1(bufA); writes Htop2(bufA, in-place), Z2(ZhB)
        gather_fused<32><<<gsz, 256, 0, stream>>>(rowptr, ecv, ZhA, bufA, W2[d], b2[d], bufA, ZhB, 32, 32, n);
        // gather L2 (+ dense L3): reads Z2(ZhB), Htop2(bufA); writes Htop3(ZhAf, stride 16), Z3(bufA own-row slots, stride 64 halfs)
        gather_fused<10><<<gsz, 256, 0, stream>>>(rowptr, ecv, ZhB, bufA, W3[d], b3[d], ZhAf, (half_t*)bufA, 16, 64, n);
        // gather L3: reads Z3(bufA), RMW Htop3->Hfin3 (ZhAf, stride 16)
        gather10<<<gsz, 256, 0, stream>>>(rowptr, ecv, (const half_t*)bufA, ZhAf, n);
        pool_graph<<<G, 256, 0, stream>>>(ZhAf, batch[d], pool, n, d * 10);
    }
    final_kernel<<<cdiv(G, 256), 256, 0, stream>>>(pool, Wf, bfv, out, G);
}

// Round 4
// 1524.822 us; speedup vs baseline: 1.4498x; 1.4498x over previous
//
#include <hip/hip_runtime.h>

#define NEG_SLOPE 0.01f
#define CSHIFT 13               // 8192 rows per coarse bucket (<=49 coarse for N<=400k)
#define MSHIFT 7                // 128 rows per mid bucket
#define MPC (1 << (CSHIFT - MSHIFT))   // 64 mids per coarse
#define MWIN 192                // window of mid-counters per split tile (straddle<=2 coarse)
#define CAP 4096                // max edges per mid bucket in csr_sort LDS
#define TILE_E 2048             // edges per split tile

typedef _Float16 half_t;
typedef _Float16 half2_t __attribute__((ext_vector_type(2)));
typedef _Float16 half4_t __attribute__((ext_vector_type(4)));

static inline int cdiv(long long a, long long b) { return (int)((a + b - 1) / b); }

__global__ __launch_bounds__(256) void zero_i32(int* __restrict__ p, int n) {
    int i = blockIdx.x * 256 + threadIdx.x;
    if (i < n) p[i] = 0;
}

// ---- coarse histogram: LDS counters, one merge atomic per (block,bucket) ----
__global__ __launch_bounds__(256) void hist_coarse(const int* __restrict__ rows, int* __restrict__ ccnt, int E) {
    __shared__ int cnt[64];
    int t = threadIdx.x;
    if (t < 64) cnt[t] = 0;
    __syncthreads();
    int base = blockIdx.x * TILE_E;
#pragma unroll
    for (int k = 0; k < TILE_E / 256; k++) {
        int e = base + k * 256 + t;
        if (e < E) atomicAdd(&cnt[rows[e] >> CSHIFT], 1);
    }
    __syncthreads();
    if (t < 64 && cnt[t] > 0) atomicAdd(&ccnt[t], cnt[t]);
}

__global__ void scan_coarse(const int* __restrict__ ccnt, int* __restrict__ cbase,
                            int* __restrict__ cfront, int NBc, int E) {
    if (threadIdx.x == 0 && blockIdx.x == 0) {
        int run = 0;
        for (int b = 0; b < NBc; b++) { cbase[b] = run; cfront[b] = run; run += ccnt[b]; }
        cbase[NBc] = E;
    }
}

// ---- pass A: LDS multisplit into coarse buckets; dense chunk writes ----
// record: ( (row & 8191) << 19 | col , val )   [13+19 = 32 bits exactly, col < 2^19]
__global__ __launch_bounds__(256) void split_coarse(
    const int* __restrict__ rows, const int* __restrict__ cols, const float* __restrict__ vals,
    int* __restrict__ cfront, int2* __restrict__ stg1, int E)
{
    __shared__ int cnt[64], gb[64];
    int t = threadIdx.x;
    if (t < 64) cnt[t] = 0;
    __syncthreads();
    int base = blockIdx.x * TILE_E;
    int myb[8], myrank[8]; int2 mycv[8];
#pragma unroll
    for (int k = 0; k < 8; k++) {
        int e = base + k * 256 + t;
        myb[k] = -1;
        if (e < E) {
            int r = rows[e];
            int b = r >> CSHIFT;
            mycv[k] = make_int2((int)(((unsigned)(r & ((1 << CSHIFT) - 1)) << 19) | (unsigned)cols[e]),
                                __float_as_int(vals[e]));
            myb[k] = b;
            myrank[k] = atomicAdd(&cnt[b], 1);
        }
    }
    __syncthreads();
    if (t < 64 && cnt[t] > 0) gb[t] = atomicAdd(&cfront[t], cnt[t]);
    __syncthreads();
#pragma unroll
    for (int k = 0; k < 8; k++)
        if (myb[k] >= 0) stg1[gb[myb[k]] + myrank[k]] = mycv[k];
}

// ---- mid histogram from coarse-sorted staging (windowed LDS counters) ----
__global__ __launch_bounds__(256) void hist_mid(
    const int2* __restrict__ stg1, const int* __restrict__ cbase_g,
    int* __restrict__ mcnt, int E, int NBc)
{
    __shared__ int cb[66];
    __shared__ int wc[MWIN];
    int t = threadIdx.x;
    for (int i = t; i <= NBc; i += 256) cb[i] = cbase_g[i];
    for (int i = t; i < MWIN; i += 256) wc[i] = 0;
    __syncthreads();
    int base = blockIdx.x * TILE_E;
    int lo = 0, hi = NBc - 1;
    while (lo < hi) { int m = (lo + hi + 1) >> 1; if (cb[m] <= base) lo = m; else hi = m - 1; }
    int winm = lo * MPC;
#pragma unroll
    for (int k = 0; k < 8; k++) {
        int e = base + k * 256 + t;
        if (e < E) {
            int b = lo;
            while (cb[b + 1] <= e) b++;
            int m = b * MPC + (int)(((unsigned)stg1[e].x >> 19) >> MSHIFT);
            int lf = m - winm;
            if (lf >= 0 && lf < MWIN) atomicAdd(&wc[lf], 1);
            else atomicAdd(&mcnt[m], 1);    // rare fallback
        }
    }
    __syncthreads();
    for (int i = t; i < MWIN; i += 256)
        if (wc[i] > 0) atomicAdd(&mcnt[winm + i], wc[i]);
}

// ---- single-block scan over mid buckets (NBm <= 3125) -> mbase, mfront ----
__global__ __launch_bounds__(256) void scan_mid(
    const int* __restrict__ mcnt, int* __restrict__ mbase,
    int* __restrict__ mfront, int NBm, int E)
{
    __shared__ int sd[256];
    __shared__ int carry;
    int t = threadIdx.x;
    if (t == 0) carry = 0;
    __syncthreads();
    for (int base = 0; base < NBm; base += 256) {
        int v = (base + t < NBm) ? mcnt[base + t] : 0;
        sd[t] = v;
        __syncthreads();
        for (int off = 1; off < 256; off <<= 1) {
            int x = (t >= off) ? sd[t - off] : 0;
            __syncthreads();
            sd[t] += x;
            __syncthreads();
        }
        int incl = sd[t] + carry;
        int excl = incl - v;
        if (base + t < NBm) { mbase[base + t] = excl; mfront[base + t] = excl; }
        __syncthreads();
        if (t == 255) carry = incl;
        __syncthreads();
    }
    if (t == 0) mbase[NBm] = E;
}

// ---- pass B: coarse-sorted staging -> mid (128-row) buckets; windowed LDS ranking ----
__global__ __launch_bounds__(256) void split_mid(
    const int2* __restrict__ stg1, const int* __restrict__ cbase_g,
    int* __restrict__ mfront, int2* __restrict__ stgm, int E, int NBc)
{
    __shared__ int cb[66];
    __shared__ int wc[MWIN], wg[MWIN];
    int t = threadIdx.x;
    for (int i = t; i <= NBc; i += 256) cb[i] = cbase_g[i];
    for (int i = t; i < MWIN; i += 256) wc[i] = 0;
    __syncthreads();
    int base = blockIdx.x * TILE_E;
    int lo = 0, hi = NBc - 1;
    while (lo < hi) { int m = (lo + hi + 1) >> 1; if (cb[m] <= base) lo = m; else hi = m - 1; }
    int winm = lo * MPC;
    int mylf[8], myrank[8]; int2 myp[8];
#pragma unroll
    for (int k = 0; k < 8; k++) {
        int e = base + k * 256 + t;
        mylf[k] = -1;
        if (e < E) {
            int b = lo;
            while (cb[b + 1] <= e) b++;
            int2 cv = stg1[e];
            int m = (b << (CSHIFT - MSHIFT)) + (int)(((unsigned)cv.x >> 19) >> MSHIFT);
            int lf = m - winm;
            if (lf >= 0 && lf < MWIN) { mylf[k] = lf; myrank[k] = atomicAdd(&wc[lf], 1); myp[k] = cv; }
            else stgm[atomicAdd(&mfront[m], 1)] = cv;   // rare fallback
        }
    }
    __syncthreads();
    for (int i = t; i < MWIN; i += 256)
        if (wc[i] > 0) wg[i] = atomicAdd(&mfront[winm + i], wc[i]);
    __syncthreads();
#pragma unroll
    for (int k = 0; k < 8; k++)
        if (mylf[k] >= 0) stgm[wg[mylf[k]] + myrank[k]] = myp[k];
}

// ---- pass C: one block per mid bucket; LDS counting sort to exact CSR ----
__global__ __launch_bounds__(256) void csr_sort(
    const int2* __restrict__ stgm, const int* __restrict__ mbase,
    int* __restrict__ rowptr, int2* __restrict__ ecv, int N)
{
    __shared__ int2 buf[CAP];
    __shared__ int cnt[128], sc[128], front[128];
    int mb = blockIdx.x, t = threadIdx.x;
    int row0 = mb << MSHIFT;
    int nrows = N - row0; if (nrows > 128) nrows = 128;
    int s = mbase[mb], eend = mbase[mb + 1];
    if (t < 128) cnt[t] = 0;
    __syncthreads();
    for (int i = s + t; i < eend; i += 256)
        atomicAdd(&cnt[((unsigned)stgm[i].x >> 19) & 127], 1);
    __syncthreads();
    if (t < 128) sc[t] = cnt[t];
    __syncthreads();
    for (int off = 1; off < 128; off <<= 1) {
        int x = (t >= off && t < 128) ? sc[t - off] : 0;
        __syncthreads();
        if (t < 128) sc[t] += x;
        __syncthreads();
    }
    if (t < 128) front[t] = sc[t] - cnt[t];
    if (t < nrows) rowptr[row0 + t] = s + sc[t] - cnt[t];
    if (t == 0 && row0 + nrows == N) rowptr[N] = eend;
    __syncthreads();
    for (int i = s + t; i < eend; i += 256) {
        int2 cv = stgm[i];
        unsigned p = (unsigned)cv.x;
        int rl = ((int)(p >> 19)) & 127;
        int2 rec = make_int2((int)(p & 0x7FFFFu), cv.y);
        int l = atomicAdd(&front[rl], 1);
        if (l < CAP) buf[l] = rec;
        else ecv[s + l] = rec;               // overflow fallback (statistically never)
    }
    __syncthreads();
    int total = eend - s; if (total > CAP) total = CAP;
    for (int l = t; l < total; l += 256) ecv[s + l] = buf[l];
}

// H[n,:] = act(in[n,:]) @ W[0:32,:] + b (stride HS) ; Z[n,:] = act(in[n,:]) @ W[32:64,:] (fp16, stride ZS)
template<int COUT, bool LRELU, int HS, int ZS>
__global__ __launch_bounds__(256) void dense_kernel(
    const float* in, const float* __restrict__ W,
    const float* __restrict__ b, float* H,
    half_t* __restrict__ Z, int N)
{
    int n = blockIdx.x * 256 + threadIdx.x;
    if (n >= N) return;
    const float* row = in + (size_t)n * 32;
    float xv[32];
#pragma unroll
    for (int f = 0; f < 32; f += 4) {
        float4 v = *(const float4*)(row + f);
        xv[f] = v.x; xv[f + 1] = v.y; xv[f + 2] = v.z; xv[f + 3] = v.w;
    }
    if (LRELU) {
#pragma unroll
        for (int f = 0; f < 32; f++) xv[f] = xv[f] > 0.f ? xv[f] : NEG_SLOPE * xv[f];
    }
    float acct[COUT], accb[COUT];
#pragma unroll
    for (int c = 0; c < COUT; c++) { acct[c] = b[c]; accb[c] = 0.f; }
#pragma unroll 4
    for (int f = 0; f < 32; f++) {
        float xf = xv[f];
#pragma unroll
        for (int c = 0; c < COUT; c++) {
            acct[c] = fmaf(xf, W[f * COUT + c], acct[c]);
            accb[c] = fmaf(xf, W[(32 + f) * COUT + c], accb[c]);
        }
    }
    float* hrow = H + (size_t)n * HS;
    half_t* zrow = Z + (size_t)n * ZS;
#pragma unroll
    for (int c = 0; c < COUT; c += 2)
        *(float2*)(hrow + c) = make_float2(acct[c], acct[c + 1]);
#pragma unroll
    for (int c = 0; c < COUT; c += 2) {
        half2_t h;
        h.x = (half_t)accb[c];
        h.y = (half_t)accb[c + 1];
        *(half2_t*)(zrow + c) = h;
    }
}

// CSR gather, 2 interleaved row-chains per thread (C=32, 8 lanes x half4) — Round-2 form (20 VGPR)
__global__ __launch_bounds__(256) void gather32(
    const int* __restrict__ rowptr, const int2* __restrict__ ecv,
    const half_t* __restrict__ Z, float* __restrict__ H, int N)
{
    int tid = blockIdx.x * 256 + threadIdx.x;
    int pr = tid >> 3, lane = tid & 7;
    int r0 = pr * 2, r1 = r0 + 1;
    if (r0 >= N) return;
    int s0 = rowptr[r0], e0 = rowptr[r0 + 1];
    int s1 = 0, e1 = 0;
    if (r1 < N) { s1 = rowptr[r1]; e1 = rowptr[r1 + 1]; }
    float ax0 = 0.f, ay0 = 0.f, az0 = 0.f, aw0 = 0.f;
    float ax1 = 0.f, ay1 = 0.f, az1 = 0.f, aw1 = 0.f;
    int i0 = s0, i1 = s1;
    while (i0 < e0 && i1 < e1) {
        int2 c0 = ecv[i0]; int2 c1 = ecv[i1];
        half4_t z0 = *(const half4_t*)(Z + (size_t)c0.x * 32 + lane * 4);
        half4_t z1 = *(const half4_t*)(Z + (size_t)c1.x * 32 + lane * 4);
        float v0 = __int_as_float(c0.y), v1 = __int_as_float(c1.y);
        ax0 = fmaf(v0, (float)z0.x, ax0); ay0 = fmaf(v0, (float)z0.y, ay0);
        az0 = fmaf(v0, (float)z0.z, az0); aw0 = fmaf(v0, (float)z0.w, aw0);
        ax1 = fmaf(v1, (float)z1.x, ax1); ay1 = fmaf(v1, (float)z1.y, ay1);
        az1 = fmaf(v1, (float)z1.z, az1); aw1 = fmaf(v1, (float)z1.w, aw1);
        i0++; i1++;
    }
    for (; i0 < e0; i0++) {
        int2 c0 = ecv[i0];
        half4_t z0 = *(const half4_t*)(Z + (size_t)c0.x * 32 + lane * 4);
        float v0 = __int_as_float(c0.y);
        ax0 = fmaf(v0, (float)z0.x, ax0); ay0 = fmaf(v0, (float)z0.y, ay0);
        az0 = fmaf(v0, (float)z0.z, az0); aw0 = fmaf(v0, (float)z0.w, aw0);
    }
    for (; i1 < e1; i1++) {
        int2 c1 = ecv[i1];
        half4_t z1 = *(const half4_t*)(Z + (size_t)c1.x * 32 + lane * 4);
        float v1 = __int_as_float(c1.y);
        ax1 = fmaf(v1, (float)z1.x, ax1); ay1 = fmaf(v1, (float)z1.y, ay1);
        az1 = fmaf(v1, (float)z1.z, az1); aw1 = fmaf(v1, (float)z1.w, aw1);
    }
    float4* hp0 = (float4*)(H + (size_t)r0 * 32 + lane * 4);
    float4 h0 = *hp0;
    h0.x += ax0; h0.y += ay0; h0.z += az0; h0.w += aw0;
    *hp0 = h0;
    if (r1 < N) {
        float4* hp1 = (float4*)(H + (size_t)r1 * 32 + lane * 4);
        float4 h1 = *hp1;
        h1.x += ax1; h1.y += ay1; h1.z += az1; h1.w += aw1;
        *hp1 = h1;
    }
}

// C=10 final gather, Z packed stride 16 halfs, Htop3 packed stride 16 floats,
// pooling fused: per-graph atomicAdd into pool sums (rows graph-sorted -> usually
// one atomic pair per thread). No Hfin write, no separate pool kernel.
__global__ __launch_bounds__(256) void gather10_pool(
    const int* __restrict__ rowptr, const int2* __restrict__ ecv,
    const half_t* __restrict__ Z, const float* __restrict__ Hbase,
    const int* __restrict__ batch, float* __restrict__ pool, int dimoff, int N)
{
    int tid = blockIdx.x * 256 + threadIdx.x;
    int pr = tid >> 3, lane = tid & 7;
    int r0 = pr * 2, r1 = r0 + 1;
    if (r0 >= N || lane >= 5) return;
    bool v1 = (r1 < N);
    int s0 = rowptr[r0], e0 = rowptr[r0 + 1];
    int s1 = 0, e1 = 0;
    if (v1) { s1 = rowptr[r1]; e1 = rowptr[r1 + 1]; }
    float ax0 = 0.f, ay0 = 0.f, ax1 = 0.f, ay1 = 0.f;
    int i0 = s0, i1 = s1;
    while (i0 < e0 && i1 < e1) {
        int2 c0 = ecv[i0]; int2 c1 = ecv[i1];
        half2_t z0 = *(const half2_t*)(Z + (size_t)c0.x * 16 + lane * 2);
        half2_t z1 = *(const half2_t*)(Z + (size_t)c1.x * 16 + lane * 2);
        float v0 = __int_as_float(c0.y), vv1 = __int_as_float(c1.y);
        ax0 = fmaf(v0, (float)z0.x, ax0); ay0 = fmaf(v0, (float)z0.y, ay0);
        ax1 = fmaf(vv1, (float)z1.x, ax1); ay1 = fmaf(vv1, (float)z1.y, ay1);
        i0++; i1++;
    }
    for (; i0 < e0; i0++) {
        int2 c0 = ecv[i0];
        half2_t z0 = *(const half2_t*)(Z + (size_t)c0.x * 16 + lane * 2);
        float v0 = __int_as_float(c0.y);
        ax0 = fmaf(v0, (float)z0.x, ax0); ay0 = fmaf(v0, (float)z0.y, ay0);
    }
    for (; i1 < e1; i1++) {
        int2 c1 = ecv[i1];
        half2_t z1 = *(const half2_t*)(Z + (size_t)c1.x * 16 + lane * 2);
        float vv1 = __int_as_float(c1.y);
        ax1 = fmaf(vv1, (float)z1.x, ax1); ay1 = fmaf(vv1, (float)z1.y, ay1);
    }
    float2 b0 = *(const float2*)(Hbase + (size_t)r0 * 16 + lane * 2);
    float h0x = b0.x + ax0, h0y = b0.y + ay0;
    int g0 = batch[r0];
    float h1x = 0.f, h1y = 0.f; int g1 = -1;
    if (v1) {
        float2 b1 = *(const float2*)(Hbase + (size_t)r1 * 16 + lane * 2);
        h1x = b1.x + ax1; h1y = b1.y + ay1;
        g1 = batch[r1];
    }
    if (v1 && g1 == g0) { h0x += h1x; h0y += h1y; }
    float* pp = pool + (size_t)g0 * 30 + dimoff + lane * 2;
    atomicAdd(pp, h0x); atomicAdd(pp + 1, h0y);
    if (v1 && g1 != g0) {
        float* pq = pool + (size_t)g1 * 30 + dimoff + lane * 2;
        atomicAdd(pq, h1x); atomicAdd(pq + 1, h1y);
    }
}

__device__ static inline int graph_count(const int* __restrict__ b, int n, int g) {
    int lo = 0, hi = n;
    while (lo < hi) { int m = (lo + hi) >> 1; if (b[m] < g) lo = m + 1; else hi = m; }
    int st = lo;
    lo = st; hi = n;
    while (lo < hi) { int m = (lo + hi) >> 1; if (b[m] < g + 1) lo = m + 1; else hi = m; }
    return lo - st;
}

// pool holds per-graph SUMS; divide by counts (binary search on sorted batch), then FC + softmax
__global__ __launch_bounds__(256) void final_kernel(
    const float* __restrict__ pool, const float* __restrict__ Wf,
    const float* __restrict__ bfv,
    const int* __restrict__ bt0, const int* __restrict__ bt1, const int* __restrict__ bt2,
    int n0, int n1, int n2, float* __restrict__ out, int G)
{
    int g = blockIdx.x * 256 + threadIdx.x;
    if (g >= G) return;
    int c0 = graph_count(bt0, n0, g);
    int c1 = graph_count(bt1, n1, g);
    int c2 = graph_count(bt2, n2, g);
    float inv0 = 1.f / (float)(c0 > 1 ? c0 : 1);
    float inv1 = 1.f / (float)(c1 > 1 ? c1 : 1);
    float inv2 = 1.f / (float)(c2 > 1 ? c2 : 1);
    float m[30];
#pragma unroll
    for (int j = 0; j < 10; j++) m[j] = pool[(size_t)g * 30 + j] * inv0;
#pragma unroll
    for (int j = 10; j < 20; j++) m[j] = pool[(size_t)g * 30 + j] * inv1;
#pragma unroll
    for (int j = 20; j < 30; j++) m[j] = pool[(size_t)g * 30 + j] * inv2;
    float lg[10];
#pragma unroll
    for (int o = 0; o < 10; o++) {
        float a = bfv[o];
#pragma unroll
        for (int j = 0; j < 30; j++) a = fmaf(m[j], Wf[j * 10 + o], a);
        lg[o] = a;
    }
    float mx = lg[0];
#pragma unroll
    for (int o = 1; o < 10; o++) mx = fmaxf(mx, lg[o]);
    float s = 0.f;
#pragma unroll
    for (int o = 0; o < 10; o++) { lg[o] = __expf(lg[o] - mx); s += lg[o]; }
    float invs = 1.f / s;
#pragma unroll
    for (int o = 0; o < 10; o++) out[(size_t)g * 10 + o] = lg[o] * invs;
}

extern "C" void kernel_launch(void* const* d_in, const int* in_sizes, int n_in,
                              void* d_out, int out_size, void* d_ws, size_t ws_size,
                              hipStream_t stream)
{
    (void)n_in; (void)ws_size;
    const float* x[3]    = {(const float*)d_in[0], (const float*)d_in[1], (const float*)d_in[2]};
    const float* vals[3] = {(const float*)d_in[3], (const float*)d_in[4], (const float*)d_in[5]};
    const int* rows[3]   = {(const int*)d_in[6], (const int*)d_in[8], (const int*)d_in[10]};
    const int* cols[3]   = {(const int*)d_in[7], (const int*)d_in[9], (const int*)d_in[11]};
    const int* batch[3]  = {(const int*)d_in[12], (const int*)d_in[13], (const int*)d_in[14]};
    const float* W1[3] = {(const float*)d_in[16], (const float*)d_in[22], (const float*)d_in[28]};
    const float* b1[3] = {(const float*)d_in[17], (const float*)d_in[23], (const float*)d_in[29]};
    const float* W2[3] = {(const float*)d_in[18], (const float*)d_in[24], (const float*)d_in[30]};
    const float* b2[3] = {(const float*)d_in[19], (const float*)d_in[25], (const float*)d_in[31]};
    const float* W3[3] = {(const float*)d_in[20], (const float*)d_in[26], (const float*)d_in[32]};
    const float* b3[3] = {(const float*)d_in[21], (const float*)d_in[27], (const float*)d_in[33]};
    const float* Wf  = (const float*)d_in[34];
    const float* bfv = (const float*)d_in[35];
    float* out = (float*)d_out;

    int N[3] = {in_sizes[0] / 32, in_sizes[1] / 32, in_sizes[2] / 32};
    int E[3] = {in_sizes[3], in_sizes[4], in_sizes[5]};
    int G = out_size / 10;
    int maxN = N[0]; if (N[1] > maxN) maxN = N[1]; if (N[2] > maxN) maxN = N[2];
    int maxE = E[0]; if (E[1] > maxE) maxE = E[1]; if (E[2] > maxE) maxE = E[2];
    int maxNBm = cdiv(maxN, 1 << MSHIFT);

    float* bufA   = (float*)d_ws;                       // layers; aliases stg1 during build
    float* bufZ   = bufA + (size_t)maxN * 32;           // Z1/Z2 (stride-32 halfs) then Htop3p+Z3p; aliases stgm
    int2*  stg1   = (int2*)bufA;                        // build-phase only
    int2*  stgm   = (int2*)bufZ;                        // build-phase only
    half_t* Zh    = (half_t*)bufZ;                      // fp16 Z view, stride 32 halfs (layers 1-2)
    float* H3p    = bufZ;                               // packed Htop3, stride 16 floats (after Z2 dead)
    half_t* Z3p   = (half_t*)(bufZ + (size_t)maxN * 16);// packed Z3, stride 16 halfs
    float* pool   = bufZ + (size_t)maxN * 32;
    int2*  ecv    = (int2*)(pool + (size_t)G * 30 + 2); // +2 for int2 alignment
    int*   rowptr = (int*)(ecv + maxE);
    int*   mcnt   = rowptr + (maxN + 1);
    int*   mbase  = mcnt + maxNBm;
    int*   mfront = mbase + (maxNBm + 1);
    int*   ccnt   = mfront + maxNBm;
    int*   cbase  = ccnt + 64;
    int*   cfront = cbase + 66;
    int zlen = 3 * maxNBm + 65;                         // mcnt + mbase + mfront + ccnt (contiguous)

    // pool accumulates via atomics across all dims -> zero once per replay, up front
    zero_i32<<<cdiv(G * 30, 256), 256, 0, stream>>>((int*)pool, G * 30);

    for (int d = 0; d < 3; d++) {
        int n = N[d], e = E[d];
        int NBc = cdiv(n, 1 << CSHIFT);
        int NBm = cdiv(n, 1 << MSHIFT);
        int ntile = cdiv(e, TILE_E);
        int gsz = cdiv((long long)cdiv(n, 2) * 8, 256);

        // --- coarse split -> mid split -> in-block CSR sort (single zero covers ccnt+mcnt) ---
        zero_i32<<<cdiv(zlen, 256), 256, 0, stream>>>(mcnt, zlen);
        hist_coarse<<<ntile, 256, 0, stream>>>(rows[d], ccnt, e);
        scan_coarse<<<1, 64, 0, stream>>>(ccnt, cbase, cfront, NBc, e);
        split_coarse<<<ntile, 256, 0, stream>>>(rows[d], cols[d], vals[d], cfront, stg1, e);
        hist_mid<<<ntile, 256, 0, stream>>>(stg1, cbase, mcnt, e, NBc);
        scan_mid<<<1, 256, 0, stream>>>(mcnt, mbase, mfront, NBm, e);
        split_mid<<<ntile, 256, 0, stream>>>(stg1, cbase, mfront, stgm, e, NBc);
        csr_sort<<<NBm, 256, 0, stream>>>(stgm, mbase, rowptr, ecv, n);

        // --- 3 layers; pure gathers (20 VGPR); final gather fuses mean-pool atomics ---
        dense_kernel<32, false, 32, 32><<<cdiv(n, 256), 256, 0, stream>>>(x[d], W1[d], b1[d], bufA, Zh, n);
        gather32<<<gsz, 256, 0, stream>>>(rowptr, ecv, Zh, bufA, n);
        dense_kernel<32, true, 32, 32><<<cdiv(n, 256), 256, 0, stream>>>(bufA, W2[d], b2[d], bufA, Zh, n);
        gather32<<<gsz, 256, 0, stream>>>(rowptr, ecv, Zh, bufA, n);
        dense_kernel<10, true, 16, 16><<<cdiv(n, 256), 256, 0, stream>>>(bufA, W3[d], b3[d], H3p, Z3p, n);
        gather10_pool<<<gsz, 256, 0, stream>>>(rowptr, ecv, Z3p, H3p, batch[d], pool, d * 10, n);
    }
    final_kernel<<<cdiv(G, 256), 256, 0, stream>>>(pool, Wf, bfv,
        batch[0], batch[1], batch[2], N[0], N[1], N[2], out, G);
}

// Round 5
// 1423.554 us; speedup vs baseline: 1.5530x; 1.0711x over previous
//
#include <hip/hip_runtime.h>

#define NEG_SLOPE 0.01f
#define CSHIFT 13               // 8192 rows per coarse bucket (<=49 coarse for N<=400k)
#define MSHIFT 7                // 128 rows per mid bucket
#define MPC (1 << (CSHIFT - MSHIFT))   // 64 mids per coarse
#define MWIN 192                // window of mid-counters per split tile (straddle<=2 coarse)
#define CAP 4096                // max edges per mid bucket in csr_sort LDS
#define TILE_E 2048             // edges per split tile

typedef _Float16 half_t;
typedef _Float16 half2_t __attribute__((ext_vector_type(2)));
typedef _Float16 half4_t __attribute__((ext_vector_type(4)));

static inline int cdiv(long long a, long long b) { return (int)((a + b - 1) / b); }

__global__ __launch_bounds__(256) void zero_i32(int* __restrict__ p, int n) {
    int i = blockIdx.x * 256 + threadIdx.x;
    if (i < n) p[i] = 0;
}

// ---- coarse histogram: LDS counters, one merge atomic per (block,bucket) ----
__global__ __launch_bounds__(256) void hist_coarse(const int* __restrict__ rows, int* __restrict__ ccnt, int E) {
    __shared__ int cnt[64];
    int t = threadIdx.x;
    if (t < 64) cnt[t] = 0;
    __syncthreads();
    int base = blockIdx.x * TILE_E;
#pragma unroll
    for (int k = 0; k < TILE_E / 256; k++) {
        int e = base + k * 256 + t;
        if (e < E) atomicAdd(&cnt[rows[e] >> CSHIFT], 1);
    }
    __syncthreads();
    if (t < 64 && cnt[t] > 0) atomicAdd(&ccnt[t], cnt[t]);
}

__global__ void scan_coarse(const int* __restrict__ ccnt, int* __restrict__ cbase,
                            int* __restrict__ cfront, int NBc, int E) {
    if (threadIdx.x == 0 && blockIdx.x == 0) {
        int run = 0;
        for (int b = 0; b < NBc; b++) { cbase[b] = run; cfront[b] = run; run += ccnt[b]; }
        cbase[NBc] = E;
    }
}

// ---- pass A: LDS multisplit into coarse buckets; dense chunk writes ----
// record: ( (row & 8191) << 19 | col , val )   [13+19 = 32 bits exactly, col < 2^19]
__global__ __launch_bounds__(256) void split_coarse(
    const int* __restrict__ rows, const int* __restrict__ cols, const float* __restrict__ vals,
    int* __restrict__ cfront, int2* __restrict__ stg1, int E)
{
    __shared__ int cnt[64], gb[64];
    int t = threadIdx.x;
    if (t < 64) cnt[t] = 0;
    __syncthreads();
    int base = blockIdx.x * TILE_E;
    int myb[8], myrank[8]; int2 mycv[8];
#pragma unroll
    for (int k = 0; k < 8; k++) {
        int e = base + k * 256 + t;
        myb[k] = -1;
        if (e < E) {
            int r = rows[e];
            int b = r >> CSHIFT;
            mycv[k] = make_int2((int)(((unsigned)(r & ((1 << CSHIFT) - 1)) << 19) | (unsigned)cols[e]),
                                __float_as_int(vals[e]));
            myb[k] = b;
            myrank[k] = atomicAdd(&cnt[b], 1);
        }
    }
    __syncthreads();
    if (t < 64 && cnt[t] > 0) gb[t] = atomicAdd(&cfront[t], cnt[t]);
    __syncthreads();
#pragma unroll
    for (int k = 0; k < 8; k++)
        if (myb[k] >= 0) stg1[gb[myb[k]] + myrank[k]] = mycv[k];
}

// ---- mid histogram from coarse-sorted staging (windowed LDS counters) ----
__global__ __launch_bounds__(256) void hist_mid(
    const int2* __restrict__ stg1, const int* __restrict__ cbase_g,
    int* __restrict__ mcnt, int E, int NBc)
{
    __shared__ int cb[66];
    __shared__ int wc[MWIN];
    int t = threadIdx.x;
    for (int i = t; i <= NBc; i += 256) cb[i] = cbase_g[i];
    for (int i = t; i < MWIN; i += 256) wc[i] = 0;
    __syncthreads();
    int base = blockIdx.x * TILE_E;
    int lo = 0, hi = NBc - 1;
    while (lo < hi) { int m = (lo + hi + 1) >> 1; if (cb[m] <= base) lo = m; else hi = m - 1; }
    int winm = lo * MPC;
#pragma unroll
    for (int k = 0; k < 8; k++) {
        int e = base + k * 256 + t;
        if (e < E) {
            int b = lo;
            while (cb[b + 1] <= e) b++;
            int m = b * MPC + (int)(((unsigned)stg1[e].x >> 19) >> MSHIFT);
            int lf = m - winm;
            if (lf >= 0 && lf < MWIN) atomicAdd(&wc[lf], 1);
            else atomicAdd(&mcnt[m], 1);    // rare fallback
        }
    }
    __syncthreads();
    for (int i = t; i < MWIN; i += 256)
        if (wc[i] > 0) atomicAdd(&mcnt[winm + i], wc[i]);
}

// ---- single-block scan over mid buckets (NBm <= 3125) -> mbase, mfront ----
__global__ __launch_bounds__(256) void scan_mid(
    const int* __restrict__ mcnt, int* __restrict__ mbase,
    int* __restrict__ mfront, int NBm, int E)
{
    __shared__ int sd[256];
    __shared__ int carry;
    int t = threadIdx.x;
    if (t == 0) carry = 0;
    __syncthreads();
    for (int base = 0; base < NBm; base += 256) {
        int v = (base + t < NBm) ? mcnt[base + t] : 0;
        sd[t] = v;
        __syncthreads();
        for (int off = 1; off < 256; off <<= 1) {
            int x = (t >= off) ? sd[t - off] : 0;
            __syncthreads();
            sd[t] += x;
            __syncthreads();
        }
        int incl = sd[t] + carry;
        int excl = incl - v;
        if (base + t < NBm) { mbase[base + t] = excl; mfront[base + t] = excl; }
        __syncthreads();
        if (t == 255) carry = incl;
        __syncthreads();
    }
    if (t == 0) mbase[NBm] = E;
}

// ---- pass B: coarse-sorted staging -> mid (128-row) buckets; windowed LDS ranking ----
__global__ __launch_bounds__(256) void split_mid(
    const int2* __restrict__ stg1, const int* __restrict__ cbase_g,
    int* __restrict__ mfront, int2* __restrict__ stgm, int E, int NBc)
{
    __shared__ int cb[66];
    __shared__ int wc[MWIN], wg[MWIN];
    int t = threadIdx.x;
    for (int i = t; i <= NBc; i += 256) cb[i] = cbase_g[i];
    for (int i = t; i < MWIN; i += 256) wc[i] = 0;
    __syncthreads();
    int base = blockIdx.x * TILE_E;
    int lo = 0, hi = NBc - 1;
    while (lo < hi) { int m = (lo + hi + 1) >> 1; if (cb[m] <= base) lo = m; else hi = m - 1; }
    int winm = lo * MPC;
    int mylf[8], myrank[8]; int2 myp[8];
#pragma unroll
    for (int k = 0; k < 8; k++) {
        int e = base + k * 256 + t;
        mylf[k] = -1;
        if (e < E) {
            int b = lo;
            while (cb[b + 1] <= e) b++;
            int2 cv = stg1[e];
            int m = (b << (CSHIFT - MSHIFT)) + (int)(((unsigned)cv.x >> 19) >> MSHIFT);
            int lf = m - winm;
            if (lf >= 0 && lf < MWIN) { mylf[k] = lf; myrank[k] = atomicAdd(&wc[lf], 1); myp[k] = cv; }
            else stgm[atomicAdd(&mfront[m], 1)] = cv;   // rare fallback
        }
    }
    __syncthreads();
    for (int i = t; i < MWIN; i += 256)
        if (wc[i] > 0) wg[i] = atomicAdd(&mfront[winm + i], wc[i]);
    __syncthreads();
#pragma unroll
    for (int k = 0; k < 8; k++)
        if (mylf[k] >= 0) stgm[wg[mylf[k]] + myrank[k]] = myp[k];
}

// ---- pass C: one block per mid bucket; LDS counting sort to exact CSR ----
__global__ __launch_bounds__(256) void csr_sort(
    const int2* __restrict__ stgm, const int* __restrict__ mbase,
    int* __restrict__ rowptr, int2* __restrict__ ecv, int N)
{
    __shared__ int2 buf[CAP];
    __shared__ int cnt[128], sc[128], front[128];
    int mb = blockIdx.x, t = threadIdx.x;
    int row0 = mb << MSHIFT;
    int nrows = N - row0; if (nrows > 128) nrows = 128;
    int s = mbase[mb], eend = mbase[mb + 1];
    if (t < 128) cnt[t] = 0;
    __syncthreads();
    for (int i = s + t; i < eend; i += 256)
        atomicAdd(&cnt[((unsigned)stgm[i].x >> 19) & 127], 1);
    __syncthreads();
    if (t < 128) sc[t] = cnt[t];
    __syncthreads();
    for (int off = 1; off < 128; off <<= 1) {
        int x = (t >= off && t < 128) ? sc[t - off] : 0;
        __syncthreads();
        if (t < 128) sc[t] += x;
        __syncthreads();
    }
    if (t < 128) front[t] = sc[t] - cnt[t];
    if (t < nrows) rowptr[row0 + t] = s + sc[t] - cnt[t];
    if (t == 0 && row0 + nrows == N) rowptr[N] = eend;
    __syncthreads();
    for (int i = s + t; i < eend; i += 256) {
        int2 cv = stgm[i];
        unsigned p = (unsigned)cv.x;
        int rl = ((int)(p >> 19)) & 127;
        int2 rec = make_int2((int)(p & 0x7FFFFu), cv.y);
        int l = atomicAdd(&front[rl], 1);
        if (l < CAP) buf[l] = rec;
        else ecv[s + l] = rec;               // overflow fallback (statistically never)
    }
    __syncthreads();
    int total = eend - s; if (total > CAP) total = CAP;
    for (int l = t; l < total; l += 256) ecv[s + l] = buf[l];
}

// H[n,:] = act(in[n,:]) @ W[0:32,:] + b (stride HS) ; Z[n,:] = act(in[n,:]) @ W[32:64,:] (fp16, stride ZS)
template<int COUT, bool LRELU, int HS, int ZS>
__global__ __launch_bounds__(256) void dense_kernel(
    const float* in, const float* __restrict__ W,
    const float* __restrict__ b, float* H,
    half_t* __restrict__ Z, int N)
{
    int n = blockIdx.x * 256 + threadIdx.x;
    if (n >= N) return;
    const float* row = in + (size_t)n * 32;
    float xv[32];
#pragma unroll
    for (int f = 0; f < 32; f += 4) {
        float4 v = *(const float4*)(row + f);
        xv[f] = v.x; xv[f + 1] = v.y; xv[f + 2] = v.z; xv[f + 3] = v.w;
    }
    if (LRELU) {
#pragma unroll
        for (int f = 0; f < 32; f++) xv[f] = xv[f] > 0.f ? xv[f] : NEG_SLOPE * xv[f];
    }
    float acct[COUT], accb[COUT];
#pragma unroll
    for (int c = 0; c < COUT; c++) { acct[c] = b[c]; accb[c] = 0.f; }
#pragma unroll 4
    for (int f = 0; f < 32; f++) {
        float xf = xv[f];
#pragma unroll
        for (int c = 0; c < COUT; c++) {
            acct[c] = fmaf(xf, W[f * COUT + c], acct[c]);
            accb[c] = fmaf(xf, W[(32 + f) * COUT + c], accb[c]);
        }
    }
    float* hrow = H + (size_t)n * HS;
    half_t* zrow = Z + (size_t)n * ZS;
#pragma unroll
    for (int c = 0; c < COUT; c += 2)
        *(float2*)(hrow + c) = make_float2(acct[c], acct[c + 1]);
#pragma unroll
    for (int c = 0; c < COUT; c += 2) {
        half2_t h;
        h.x = (half_t)accb[c];
        h.y = (half_t)accb[c + 1];
        *(half2_t*)(zrow + c) = h;
    }
}

// CSR gather, 2 interleaved row-chains per thread (C=32, 8 lanes x half4) — 20 VGPR form
__global__ __launch_bounds__(256) void gather32(
    const int* __restrict__ rowptr, const int2* __restrict__ ecv,
    const half_t* __restrict__ Z, float* __restrict__ H, int N)
{
    int tid = blockIdx.x * 256 + threadIdx.x;
    int pr = tid >> 3, lane = tid & 7;
    int r0 = pr * 2, r1 = r0 + 1;
    if (r0 >= N) return;
    int s0 = rowptr[r0], e0 = rowptr[r0 + 1];
    int s1 = 0, e1 = 0;
    if (r1 < N) { s1 = rowptr[r1]; e1 = rowptr[r1 + 1]; }
    float ax0 = 0.f, ay0 = 0.f, az0 = 0.f, aw0 = 0.f;
    float ax1 = 0.f, ay1 = 0.f, az1 = 0.f, aw1 = 0.f;
    int i0 = s0, i1 = s1;
    while (i0 < e0 && i1 < e1) {
        int2 c0 = ecv[i0]; int2 c1 = ecv[i1];
        half4_t z0 = *(const half4_t*)(Z + (size_t)c0.x * 32 + lane * 4);
        half4_t z1 = *(const half4_t*)(Z + (size_t)c1.x * 32 + lane * 4);
        float v0 = __int_as_float(c0.y), v1 = __int_as_float(c1.y);
        ax0 = fmaf(v0, (float)z0.x, ax0); ay0 = fmaf(v0, (float)z0.y, ay0);
        az0 = fmaf(v0, (float)z0.z, az0); aw0 = fmaf(v0, (float)z0.w, aw0);
        ax1 = fmaf(v1, (float)z1.x, ax1); ay1 = fmaf(v1, (float)z1.y, ay1);
        az1 = fmaf(v1, (float)z1.z, az1); aw1 = fmaf(v1, (float)z1.w, aw1);
        i0++; i1++;
    }
    for (; i0 < e0; i0++) {
        int2 c0 = ecv[i0];
        half4_t z0 = *(const half4_t*)(Z + (size_t)c0.x * 32 + lane * 4);
        float v0 = __int_as_float(c0.y);
        ax0 = fmaf(v0, (float)z0.x, ax0); ay0 = fmaf(v0, (float)z0.y, ay0);
        az0 = fmaf(v0, (float)z0.z, az0); aw0 = fmaf(v0, (float)z0.w, aw0);
    }
    for (; i1 < e1; i1++) {
        int2 c1 = ecv[i1];
        half4_t z1 = *(const half4_t*)(Z + (size_t)c1.x * 32 + lane * 4);
        float v1 = __int_as_float(c1.y);
        ax1 = fmaf(v1, (float)z1.x, ax1); ay1 = fmaf(v1, (float)z1.y, ay1);
        az1 = fmaf(v1, (float)z1.z, az1); aw1 = fmaf(v1, (float)z1.w, aw1);
    }
    float4* hp0 = (float4*)(H + (size_t)r0 * 32 + lane * 4);
    float4 h0 = *hp0;
    h0.x += ax0; h0.y += ay0; h0.z += az0; h0.w += aw0;
    *hp0 = h0;
    if (r1 < N) {
        float4* hp1 = (float4*)(H + (size_t)r1 * 32 + lane * 4);
        float4 h1 = *hp1;
        h1.x += ax1; h1.y += ay1; h1.z += az1; h1.w += aw1;
        *hp1 = h1;
    }
}

// C=10 final gather: Z packed stride 16 halfs, H packed stride 16 floats, RMW (no atomics)
__global__ __launch_bounds__(256) void gather10(
    const int* __restrict__ rowptr, const int2* __restrict__ ecv,
    const half_t* __restrict__ Z, float* __restrict__ H, int N)
{
    int tid = blockIdx.x * 256 + threadIdx.x;
    int pr = tid >> 3, lane = tid & 7;
    int r0 = pr * 2, r1 = r0 + 1;
    if (r0 >= N || lane >= 5) return;
    int s0 = rowptr[r0], e0 = rowptr[r0 + 1];
    int s1 = 0, e1 = 0;
    if (r1 < N) { s1 = rowptr[r1]; e1 = rowptr[r1 + 1]; }
    float ax0 = 0.f, ay0 = 0.f, ax1 = 0.f, ay1 = 0.f;
    int i0 = s0, i1 = s1;
    while (i0 < e0 && i1 < e1) {
        int2 c0 = ecv[i0]; int2 c1 = ecv[i1];
        half2_t z0 = *(const half2_t*)(Z + (size_t)c0.x * 16 + lane * 2);
        half2_t z1 = *(const half2_t*)(Z + (size_t)c1.x * 16 + lane * 2);
        float v0 = __int_as_float(c0.y), v1 = __int_as_float(c1.y);
        ax0 = fmaf(v0, (float)z0.x, ax0); ay0 = fmaf(v0, (float)z0.y, ay0);
        ax1 = fmaf(v1, (float)z1.x, ax1); ay1 = fmaf(v1, (float)z1.y, ay1);
        i0++; i1++;
    }
    for (; i0 < e0; i0++) {
        int2 c0 = ecv[i0];
        half2_t z0 = *(const half2_t*)(Z + (size_t)c0.x * 16 + lane * 2);
        float v0 = __int_as_float(c0.y);
        ax0 = fmaf(v0, (float)z0.x, ax0); ay0 = fmaf(v0, (float)z0.y, ay0);
    }
    for (; i1 < e1; i1++) {
        int2 c1 = ecv[i1];
        half2_t z1 = *(const half2_t*)(Z + (size_t)c1.x * 16 + lane * 2);
        float v1 = __int_as_float(c1.y);
        ax1 = fmaf(v1, (float)z1.x, ax1); ay1 = fmaf(v1, (float)z1.y, ay1);
    }
    float* hp0 = H + (size_t)r0 * 16 + lane * 2;
    hp0[0] += ax0; hp0[1] += ay0;
    if (r1 < N) {
        float* hp1 = H + (size_t)r1 * 16 + lane * 2;
        hp1[0] += ax1; hp1[1] += ay1;
    }
}

// one block per graph; batch is sorted -> binary search node range, no atomics; H stride 16
__global__ __launch_bounds__(256) void pool_graph(
    const float* __restrict__ H, const int* __restrict__ batch,
    float* __restrict__ pool, int N, int dimoff)
{
    int g = blockIdx.x;
    int lo = 0, hi = N;
    while (lo < hi) { int mid = (lo + hi) >> 1; if (batch[mid] < g) lo = mid + 1; else hi = mid; }
    int start = lo;
    lo = start; hi = N;
    while (lo < hi) { int mid = (lo + hi) >> 1; if (batch[mid] < g + 1) lo = mid + 1; else hi = mid; }
    int end = lo;
    int t = threadIdx.x, f = t & 15, chain = t >> 4;
    __shared__ float sd[256];
    float acc = 0.f;
    if (f < 10) {
        for (int i = start + chain; i < end; i += 16) acc += H[(size_t)i * 16 + f];
    }
    sd[t] = acc; __syncthreads();
    if (chain == 0 && f < 10) {
        float s = 0.f;
#pragma unroll
        for (int k = 0; k < 16; k++) s += sd[k * 16 + f];
        int c = end - start;
        float inv = 1.f / (float)(c > 1 ? c : 1);
        pool[(size_t)g * 30 + dimoff + f] = s * inv;
    }
}

__global__ __launch_bounds__(256) void final_kernel(
    const float* __restrict__ pool, const float* __restrict__ Wf,
    const float* __restrict__ bfv, float* __restrict__ out, int G)
{
    int g = blockIdx.x * 256 + threadIdx.x;
    if (g >= G) return;
    float m[30];
#pragma unroll
    for (int j = 0; j < 30; j++) m[j] = pool[(size_t)g * 30 + j];
    float lg[10];
#pragma unroll
    for (int o = 0; o < 10; o++) {
        float a = bfv[o];
#pragma unroll
        for (int j = 0; j < 30; j++) a = fmaf(m[j], Wf[j * 10 + o], a);
        lg[o] = a;
    }
    float mx = lg[0];
#pragma unroll
    for (int o = 1; o < 10; o++) mx = fmaxf(mx, lg[o]);
    float s = 0.f;
#pragma unroll
    for (int o = 0; o < 10; o++) { lg[o] = __expf(lg[o] - mx); s += lg[o]; }
    float invs = 1.f / s;
#pragma unroll
    for (int o = 0; o < 10; o++) out[(size_t)g * 10 + o] = lg[o] * invs;
}

extern "C" void kernel_launch(void* const* d_in, const int* in_sizes, int n_in,
                              void* d_out, int out_size, void* d_ws, size_t ws_size,
                              hipStream_t stream)
{
    (void)n_in; (void)ws_size;
    const float* x[3]    = {(const float*)d_in[0], (const float*)d_in[1], (const float*)d_in[2]};
    const float* vals[3] = {(const float*)d_in[3], (const float*)d_in[4], (const float*)d_in[5]};
    const int* rows[3]   = {(const int*)d_in[6], (const int*)d_in[8], (const int*)d_in[10]};
    const int* cols[3]   = {(const int*)d_in[7], (const int*)d_in[9], (const int*)d_in[11]};
    const int* batch[3]  = {(const int*)d_in[12], (const int*)d_in[13], (const int*)d_in[14]};
    const float* W1[3] = {(const float*)d_in[16], (const float*)d_in[22], (const float*)d_in[28]};
    const float* b1[3] = {(const float*)d_in[17], (const float*)d_in[23], (const float*)d_in[29]};
    const float* W2[3] = {(const float*)d_in[18], (const float*)d_in[24], (const float*)d_in[30]};
    const float* b2[3] = {(const float*)d_in[19], (const float*)d_in[25], (const float*)d_in[31]};
    const float* W3[3] = {(const float*)d_in[20], (const float*)d_in[26], (const float*)d_in[32]};
    const float* b3[3] = {(const float*)d_in[21], (const float*)d_in[27], (const float*)d_in[33]};
    const float* Wf  = (const float*)d_in[34];
    const float* bfv = (const float*)d_in[35];
    float* out = (float*)d_out;

    int N[3] = {in_sizes[0] / 32, in_sizes[1] / 32, in_sizes[2] / 32};
    int E[3] = {in_sizes[3], in_sizes[4], in_sizes[5]};
    int G = out_size / 10;
    int maxN = N[0]; if (N[1] > maxN) maxN = N[1]; if (N[2] > maxN) maxN = N[2];
    int maxE = E[0]; if (E[1] > maxE) maxE = E[1]; if (E[2] > maxE) maxE = E[2];
    int maxNBm = cdiv(maxN, 1 << MSHIFT);

    float* bufA   = (float*)d_ws;                       // layers; aliases stg1 during build
    float* bufZ   = bufA + (size_t)maxN * 32;           // Z1/Z2 (stride-32 halfs) then H3p+Z3p; aliases stgm
    int2*  stg1   = (int2*)bufA;                        // build-phase only
    int2*  stgm   = (int2*)bufZ;                        // build-phase only
    half_t* Zh    = (half_t*)bufZ;                      // fp16 Z view, stride 32 halfs (layers 1-2)
    float* H3p    = bufZ;                               // packed Htop3/Hfin3, stride 16 floats (after Z2 dead)
    half_t* Z3p   = (half_t*)(bufZ + (size_t)maxN * 16);// packed Z3, stride 16 halfs
    float* pool   = bufZ + (size_t)maxN * 32;
    int2*  ecv    = (int2*)(pool + (size_t)G * 30 + 2); // +2 for int2 alignment
    int*   rowptr = (int*)(ecv + maxE);
    int*   mcnt   = rowptr + (maxN + 1);
    int*   mbase  = mcnt + maxNBm;
    int*   mfront = mbase + (maxNBm + 1);
    int*   ccnt   = mfront + maxNBm;
    int*   cbase  = ccnt + 64;
    int*   cfront = cbase + 66;
    int zlen = 3 * maxNBm + 65;                         // mcnt + mbase + mfront + ccnt (contiguous)

    for (int d = 0; d < 3; d++) {
        int n = N[d], e = E[d];
        int NBc = cdiv(n, 1 << CSHIFT);
        int NBm = cdiv(n, 1 << MSHIFT);
        int ntile = cdiv(e, TILE_E);
        int gsz = cdiv((long long)cdiv(n, 2) * 8, 256);

        // --- coarse split -> mid split -> in-block CSR sort (single zero covers ccnt+mcnt) ---
        zero_i32<<<cdiv(zlen, 256), 256, 0, stream>>>(mcnt, zlen);
        hist_coarse<<<ntile, 256, 0, stream>>>(rows[d], ccnt, e);
        scan_coarse<<<1, 64, 0, stream>>>(ccnt, cbase, cfront, NBc, e);
        split_coarse<<<ntile, 256, 0, stream>>>(rows[d], cols[d], vals[d], cfront, stg1, e);
        hist_mid<<<ntile, 256, 0, stream>>>(stg1, cbase, mcnt, e, NBc);
        scan_mid<<<1, 256, 0, stream>>>(mcnt, mbase, mfront, NBm, e);
        split_mid<<<ntile, 256, 0, stream>>>(stg1, cbase, mfront, stgm, e, NBc);
        csr_sort<<<NBm, 256, 0, stream>>>(stgm, mbase, rowptr, ecv, n);

        // --- 3 layers; pure gathers (low VGPR, high occupancy); streaming pool (no atomics) ---
        dense_kernel<32, false, 32, 32><<<cdiv(n, 256), 256, 0, stream>>>(x[d], W1[d], b1[d], bufA, Zh, n);
        gather32<<<gsz, 256, 0, stream>>>(rowptr, ecv, Zh, bufA, n);
        dense_kernel<32, true, 32, 32><<<cdiv(n, 256), 256, 0, stream>>>(bufA, W2[d], b2[d], bufA, Zh, n);
        gather32<<<gsz, 256, 0, stream>>>(rowptr, ecv, Zh, bufA, n);
        dense_kernel<10, true, 16, 16><<<cdiv(n, 256), 256, 0, stream>>>(bufA, W3[d], b3[d], H3p, Z3p, n);
        gather10<<<gsz, 256, 0, stream>>>(rowptr, ecv, Z3p, H3p, n);
        pool_graph<<<G, 256, 0, stream>>>(H3p, batch[d], pool, n, d * 10);
    }
    final_kernel<<<cdiv(G, 256), 256, 0, stream>>>(pool, Wf, bfv, out, G);
}